// Round 11
// baseline (238.454 us; speedup 1.0000x reference)
//
#include <hip/hip_runtime.h>

// LIF neuron scan: x[T,B,D] f32, v0[D] f32 -> spikes[T,B,D] f32.
// T=512, B=64, D=1024. tau=0.5 (exact mul), threshold=1.0, v_reset=0.0.
//
// R1: 1 thread/chain, unroll16          -> ~80us, 2.5 TB/s (W~3.6 in flight)
// R4/R6: ping-pong / triple-buffer ILP  -> ~77us. inert.
// R7: 4x TLP (T-chunk + 64-step warmup) -> 80us, 2.77 TB/s, W collapsed to ~1
//     (templated ping-pong re-rolled by compiler; TLP gain exactly canceled).
// R8-R10: attack bytes/load: 4 chains/thread via 16B vectors (1KB/wave-load,
//     same width as the 6.7 TB/s fill kernel's dwordx4). Keep C=4 chunks +
//     64-step warmup -> still 1024 waves. Flat unroll-16 body:
//     in-flight ~ 1024 x 3.6 x 1KB = 3.7MB > 2.4MB BW-latency product.
//     R9:  __builtin_nontemporal_store needs NATIVE vector (ext_vector_type).
//     R10: vector elements can't bind to float& -> state in plain float[4].

constexpr int T_STEPS  = 512;
constexpr int B_DIM    = 64;
constexpr int D_DIM    = 1024;
constexpr int N_CHAIN  = B_DIM * D_DIM;      // 65536 chains
constexpr int VEC      = 4;                  // chains per thread (16B vector)
constexpr int NT_VEC   = N_CHAIN / VEC;      // 16384 vector columns
constexpr int C_CHUNKS = 4;
constexpr int T_CHUNK  = T_STEPS / C_CHUNKS; // 128
constexpr int K_WARM   = 64;                 // speculative warm-up steps

typedef float v4f __attribute__((ext_vector_type(4)));   // native 16B vector

__global__ __launch_bounds__(256)
void lif_scan_kernel(const float* __restrict__ x,
                     const float* __restrict__ v0,
                     float* __restrict__ out) {
    // 256 blocks: low 6 bits pick the column slab (64 blocks x 256 thr
    // cover all 16384 vector-columns), high 2 bits pick the T-chunk.
    const int col   = ((blockIdx.x & 63) << 8) + threadIdx.x;  // 0..16383
    const int chunk = blockIdx.x >> 6;                         // 0..3

    const v4f* xp = (const v4f*)x   + col;   // stride NT_VEC per t
    v4f*       op = (v4f*)      out + col;

    const int d0 = (col * VEC) & (D_DIM - 1);      // multiple of 4

    float v[VEC];                                   // state in VGPRs
    const int tstart = chunk * T_CHUNK;

    if (chunk == 0) {
        const v4f vi = *(const v4f*)(v0 + d0);     // exact start
        v[0] = vi.x; v[1] = vi.y; v[2] = vi.z; v[3] = vi.w;
    } else {
#pragma unroll
        for (int i = 0; i < VEC; ++i) v[i] = 0.0f; // speculative start
        // Warm-up: tau=0.5 halves state error each step; any shared reset
        // snaps v to exact 0.0. 64 steps -> bit-exact whp (R7: absmax=0).
#pragma unroll 16
        for (int t = tstart - K_WARM; t < tstart; ++t) {
            const v4f xv = xp[(size_t)t * NT_VEC];
            const float xs[VEC] = {xv.x, xv.y, xv.z, xv.w};
#pragma unroll
            for (int i = 0; i < VEC; ++i) {
                float vi = v[i] * 0.5f + xs[i];    // exact: tau = 0.5
                v[i] = (vi >= 1.0f) ? 0.0f : vi;
            }
        }
    }

    // Main: 128 steps, 1KB/wave load + 1KB/wave nt store per step.
#pragma unroll 16
    for (int t = tstart; t < tstart + T_CHUNK; ++t) {
        const v4f xv = xp[(size_t)t * NT_VEC];
        const float xs[VEC] = {xv.x, xv.y, xv.z, xv.w};
        float ss[VEC];
#pragma unroll
        for (int i = 0; i < VEC; ++i) {
            float vi = v[i] * 0.5f + xs[i];        // exact: tau = 0.5
            const bool sp = (vi >= 1.0f);
            ss[i] = sp ? 1.0f : 0.0f;
            v[i]  = sp ? 0.0f : vi;
        }
        v4f s;
        s.x = ss[0]; s.y = ss[1]; s.z = ss[2]; s.w = ss[3];
        __builtin_nontemporal_store(s, op + (size_t)t * NT_VEC);
    }
}

extern "C" void kernel_launch(void* const* d_in, const int* in_sizes, int n_in,
                              void* d_out, int out_size, void* d_ws, size_t ws_size,
                              hipStream_t stream) {
    const float* x   = (const float*)d_in[0];
    const float* v0  = (const float*)d_in[1];
    float*       out = (float*)d_out;

    dim3 block(256);
    dim3 grid(C_CHUNKS * (NT_VEC / 256));   // 4 x 64 = 256 blocks, 1024 waves
    hipLaunchKernelGGL(lif_scan_kernel, grid, block, 0, stream, x, v0, out);
}